// Round 8
// baseline (406.302 us; speedup 1.0000x reference)
//
#include <hip/hip_runtime.h>

// GAT 2-layer forward on MI355X.
// Round 8: r7 crashed — __ballot is per-wave, so the t<64 gate made waves 1-3
// always report is64=1; harness edges are int32 -> eg64[E+i] OOB reads -> fault.
// Fix: every wave samples the SAME 64 in-range indices (base + (t&63),
// base=clamp(i0,0,E-64)) -> identical ballots -> block-uniform is64.
// Rest identical to r7:
//  - CHUNK 4096 / CB_SZ 256 (2x build-kernel grids; r6 build latency-bound)
//  - agg1+gemm2+attn2+pack fused, x1 only in LDS
//  - 9 dispatches
// Payloads: h1h fp16 64B rows, h2h fp16 128B-padded rows.

#define DEVFN __device__ __forceinline__
#define CB_SHIFT 8
#define CB_SZ 256
#define CHUNK 4096
#define A2B 250  // agg2 active threads per block (multiple of 10)

DEVFN unsigned short f2h(float f) {
  _Float16 h = (_Float16)f;
  unsigned short u;
  __builtin_memcpy(&u, &h, 2);
  return u;
}
DEVFN float h2f(unsigned short u) {
  _Float16 h;
  __builtin_memcpy(&h, &u, 2);
  return (float)h;
}

DEVFN void read_edge(const long long* eg64, const int* eg32, int is64, int E,
                     int i, int& s, int& d) {
  if (i >= E) { s = d = i - E; return; }
  if (is64) { s = (int)eg64[i]; d = (int)eg64[E + i]; }
  else      { s = eg32[i];      d = eg32[E + i]; }
}

// block-uniform edge dtype detection: EVERY wave samples the same 64 in-range
// indices (int64 data => high words all zero; int32 data => random src values).
DEVFN int detect64(const int* eg32, int E, int i0, int t) {
  int base = i0;
  if (base > E - 64) base = E - 64;
  if (base < 0) base = 0;
  int i = base + (t & 63);
  unsigned long long m = __ballot((i < E) && (eg32[2 * i + 1] != 0));
  return m == 0ull;
}

// ---------------- generic scan (blocks of 1024) for chunk histograms --------
__global__ void scan_blocks(const int* __restrict__ cnt, int* __restrict__ rp,
                            int* __restrict__ bsum, int n) {
  __shared__ int buf[2][1024];
  int t = threadIdx.x;
  int gid = blockIdx.x * 1024 + t;
  int v = (gid < n) ? cnt[gid] : 0;
  buf[0][t] = v;
  __syncthreads();
  int pin = 0;
  for (int offd = 1; offd < 1024; offd <<= 1) {
    int nv = buf[pin][t];
    if (t >= offd) nv += buf[pin][t - offd];
    buf[1 - pin][t] = nv;
    pin = 1 - pin;
    __syncthreads();
  }
  int inc = buf[pin][t];
  if (gid < n) rp[gid] = inc - v;  // exclusive within block
  if (t == 1023) bsum[blockIdx.x] = inc;
}

__global__ void scan_sums(const int* bsum, int* boff, int nb) {
  if (blockIdx.x == 0 && threadIdx.x == 0) {
    int r = 0;
    for (int i = 0; i < nb; i++) { boff[i] = r; r += bsum[i]; }
  }
}

__global__ void scan_add(int* rp, const int* boff, int n, int total) {
  int i = blockIdx.x * 1024 + threadIdx.x;
  if (i < n) rp[i] = rp[i] + boff[blockIdx.x];
  if (i == 0) rp[n] = total;
}

// ---------------- CSR build (atomic-free multisplit) ----------------
__global__ __launch_bounds__(256) void chunk_hist(const long long* eg64,
                                                  const int* eg32,
                                                  int E, int N, int NWG,
                                                  int* __restrict__ histg) {
  __shared__ int lh[512];
  int w = blockIdx.x, t = threadIdx.x;
  int NB2 = (N + CB_SZ - 1) / CB_SZ;
  for (int j = t; j < NB2; j += 256) lh[j] = 0;
  int i0 = w * CHUNK;
  int is64 = detect64(eg32, E, i0, t);
  __syncthreads();
  int EN = E + N;
  int i1 = i0 + CHUNK; if (i1 > EN) i1 = EN;
  for (int i = i0 + t; i < i1; i += 256) {
    int d;
    if (i >= E) d = i - E;
    else d = is64 ? (int)eg64[E + i] : eg32[E + i];
    atomicAdd(&lh[d >> CB_SHIFT], 1);
  }
  __syncthreads();
  for (int b = t; b < NB2; b += 256) histg[b * NWG + w] = lh[b];
}

__global__ __launch_bounds__(256) void chunk_scatter(const long long* eg64,
                                                     const int* eg32,
                                                     int E, int N, int NWG,
                                                     const int* __restrict__ hists,
                                                     int* __restrict__ tmp) {
  __shared__ int lcur[512];
  int w = blockIdx.x, t = threadIdx.x;
  int NB2 = (N + CB_SZ - 1) / CB_SZ;
  for (int b = t; b < NB2; b += 256) lcur[b] = hists[b * NWG + w];
  int i0 = w * CHUNK;
  int is64 = detect64(eg32, E, i0, t);
  __syncthreads();
  int EN = E + N;
  int i1 = i0 + CHUNK; if (i1 > EN) i1 = EN;
  for (int i = i0 + t; i < i1; i += 256) {
    int s, d;
    read_edge(eg64, eg32, is64, E, i, s, d);
    int b = d >> CB_SHIFT;
    int pos = atomicAdd(&lcur[b], 1);
    tmp[pos] = (s << CB_SHIFT) | (d & (CB_SZ - 1));
  }
}

// per-bucket: node counts + in-LDS scan -> rp; scatter tmp -> csr
__global__ __launch_bounds__(256) void bucket_rp_sort(const int* __restrict__ hists,
                                                      int NWG,
                                                      const int* __restrict__ tmp,
                                                      int* __restrict__ rp,
                                                      int* __restrict__ csr,
                                                      int N, int EN) {
  __shared__ int lc[256];
  __shared__ int ps[256];
  __shared__ int lcur[256];
  int b = blockIdx.x, t = threadIdx.x;
  lc[t] = 0;
  __syncthreads();
  int w0 = hists[b * NWG];
  int w1 = hists[(b + 1) * NWG];  // last bucket reads hists[NB2*NWG] == EN
  for (int p = w0 + t; p < w1; p += 256)
    atomicAdd(&lc[tmp[p] & (CB_SZ - 1)], 1);
  __syncthreads();
  int my = lc[t];
  ps[t] = my;
  __syncthreads();
  for (int off = 1; off < 256; off <<= 1) {
    int v = ps[t];
    int u = (t >= off) ? ps[t - off] : 0;
    __syncthreads();
    ps[t] = v + u;
    __syncthreads();
  }
  int base = w0 + ps[t] - my;  // exclusive prefix within bucket
  lcur[t] = base;
  int n0 = b * CB_SZ + t;
  if (n0 < N) rp[n0] = base;
  if (b == (int)gridDim.x - 1 && t == 0) rp[N] = EN;
  __syncthreads();
  for (int p = w0 + t; p < w1; p += 256) {
    int e = tmp[p];
    int pos = atomicAdd(&lcur[e & (CB_SZ - 1)], 1);
    csr[pos] = e >> CB_SHIFT;
  }
}

// ---------------- fused GEMM + attn + fp16 pack, layer 1 ----------------
__global__ __launch_bounds__(256) void gemm1f(const float* __restrict__ X,
                                              const float* __restrict__ W,
                                              const float* __restrict__ att_s,
                                              const float* __restrict__ att_d,
                                              uint4* __restrict__ h1h,
                                              float* __restrict__ as1,
                                              float* __restrict__ ad1, int N) {
  __shared__ float Wl[128 * 32];
  __shared__ float Asl[32], Adl[32];
  int t = threadIdx.x;
  for (int i = t; i < 1024; i += 256)
    ((float4*)Wl)[i] = ((const float4*)W)[i];
  if (t < 32) { Asl[t] = att_s[t]; Adl[t] = att_d[t]; }
  __syncthreads();
  int n = blockIdx.x * 256 + t;
  if (n >= N) return;
  const float4* X4 = (const float4*)(X + (size_t)n * 128);
  float acc[32];
#pragma unroll
  for (int c = 0; c < 32; c++) acc[c] = 0.f;
  for (int k4 = 0; k4 < 32; k4++) {
    float4 x = X4[k4];
    const float4* w4 = (const float4*)(Wl + k4 * 128);
#pragma unroll
    for (int c4 = 0; c4 < 8; c4++) {
      float4 w0 = w4[c4], w1 = w4[8 + c4], w2 = w4[16 + c4], w3 = w4[24 + c4];
      float* A = acc + c4 * 4;
      A[0] = fmaf(x.x, w0.x, A[0]); A[1] = fmaf(x.x, w0.y, A[1]);
      A[2] = fmaf(x.x, w0.z, A[2]); A[3] = fmaf(x.x, w0.w, A[3]);
      A[0] = fmaf(x.y, w1.x, A[0]); A[1] = fmaf(x.y, w1.y, A[1]);
      A[2] = fmaf(x.y, w1.z, A[2]); A[3] = fmaf(x.y, w1.w, A[3]);
      A[0] = fmaf(x.z, w2.x, A[0]); A[1] = fmaf(x.z, w2.y, A[1]);
      A[2] = fmaf(x.z, w2.z, A[2]); A[3] = fmaf(x.z, w2.w, A[3]);
      A[0] = fmaf(x.w, w3.x, A[0]); A[1] = fmaf(x.w, w3.y, A[1]);
      A[2] = fmaf(x.w, w3.z, A[2]); A[3] = fmaf(x.w, w3.w, A[3]);
    }
  }
  float s0 = 0.f, d0 = 0.f, s1 = 0.f, d1 = 0.f;
#pragma unroll
  for (int c = 0; c < 16; c++) {
    s0 = fmaf(acc[c], Asl[c], s0);
    d0 = fmaf(acc[c], Adl[c], d0);
    s1 = fmaf(acc[16 + c], Asl[16 + c], s1);
    d1 = fmaf(acc[16 + c], Adl[16 + c], d1);
  }
  as1[n * 2] = s0; as1[n * 2 + 1] = s1;
  ad1[n * 2] = d0; ad1[n * 2 + 1] = d1;
#pragma unroll
  for (int j = 0; j < 4; j++) {
    uint4 u;
    u.x = (unsigned)f2h(acc[j * 8 + 0]) | ((unsigned)f2h(acc[j * 8 + 1]) << 16);
    u.y = (unsigned)f2h(acc[j * 8 + 2]) | ((unsigned)f2h(acc[j * 8 + 3]) << 16);
    u.z = (unsigned)f2h(acc[j * 8 + 4]) | ((unsigned)f2h(acc[j * 8 + 5]) << 16);
    u.w = (unsigned)f2h(acc[j * 8 + 6]) | ((unsigned)f2h(acc[j * 8 + 7]) << 16);
    h1h[(size_t)n * 4 + j] = u;
  }
}

// ------- fused agg1 (split-K, shfl) + gemm2 + attn2 + fp16 pack -------------
// block = 32 nodes x 8 threads; r=(half,cq); x1 row lives only in LDS.
__global__ __launch_bounds__(256) void agg1_gemm2(
    const int* __restrict__ rp, const int* __restrict__ csr,
    const float* __restrict__ as, const float* __restrict__ ad,
    const uint4* __restrict__ h1h, const float* __restrict__ b1,
    const float* __restrict__ W2, const float* __restrict__ as2w,
    const float* __restrict__ ad2w, uint4* __restrict__ h2h,
    float* __restrict__ as2, float* __restrict__ ad2, int N) {
  __shared__ float Wl[32 * 40];
  __shared__ float As2l[40], Ad2l[40];
  __shared__ float x1t[32][33];
  __shared__ float h2r[32][41];
  int t = threadIdx.x;
  for (int i = t; i < 320; i += 256)
    ((float4*)Wl)[i] = ((const float4*)W2)[i];
  if (t < 40) { As2l[t] = as2w[t]; Ad2l[t] = ad2w[t]; }
  int nl = t >> 3, r = t & 7;
  int half = r >> 2, cq = r & 3;
  int h = cq >> 1;
  int n = blockIdx.x * 32 + nl;
  float acc[8] = {0, 0, 0, 0, 0, 0, 0, 0};
  float ssum = 0.f;
  if (n < N) {
    int p0 = rp[n], p1 = rp[n + 1];
    float adv = ad[n * 2 + h];
    int p = p0 + half;
    for (; p + 2 < p1; p += 4) {
      int s0 = csr[p], s1 = csr[p + 2];
      float e0 = as[s0 * 2 + h] + adv;
      float e1 = as[s1 * 2 + h] + adv;
      uint4 u0 = h1h[(size_t)s0 * 4 + cq];
      uint4 u1 = h1h[(size_t)s1 * 4 + cq];
      e0 = e0 > 0.f ? e0 : 0.2f * e0;
      e1 = e1 > 0.f ? e1 : 0.2f * e1;
      float x0 = __expf(e0), x1e = __expf(e1);
      ssum += x0 + x1e;
      acc[0] = fmaf(x0, h2f(u0.x & 0xffff), acc[0]);
      acc[1] = fmaf(x0, h2f(u0.x >> 16),    acc[1]);
      acc[2] = fmaf(x0, h2f(u0.y & 0xffff), acc[2]);
      acc[3] = fmaf(x0, h2f(u0.y >> 16),    acc[3]);
      acc[4] = fmaf(x0, h2f(u0.z & 0xffff), acc[4]);
      acc[5] = fmaf(x0, h2f(u0.z >> 16),    acc[5]);
      acc[6] = fmaf(x0, h2f(u0.w & 0xffff), acc[6]);
      acc[7] = fmaf(x0, h2f(u0.w >> 16),    acc[7]);
      acc[0] = fmaf(x1e, h2f(u1.x & 0xffff), acc[0]);
      acc[1] = fmaf(x1e, h2f(u1.x >> 16),    acc[1]);
      acc[2] = fmaf(x1e, h2f(u1.y & 0xffff), acc[2]);
      acc[3] = fmaf(x1e, h2f(u1.y >> 16),    acc[3]);
      acc[4] = fmaf(x1e, h2f(u1.z & 0xffff), acc[4]);
      acc[5] = fmaf(x1e, h2f(u1.z >> 16),    acc[5]);
      acc[6] = fmaf(x1e, h2f(u1.w & 0xffff), acc[6]);
      acc[7] = fmaf(x1e, h2f(u1.w >> 16),    acc[7]);
    }
    for (; p < p1; p += 2) {
      int s = csr[p];
      float e = as[s * 2 + h] + adv;
      uint4 u = h1h[(size_t)s * 4 + cq];
      e = e > 0.f ? e : 0.2f * e;
      float ex = __expf(e);
      ssum += ex;
      acc[0] = fmaf(ex, h2f(u.x & 0xffff), acc[0]);
      acc[1] = fmaf(ex, h2f(u.x >> 16),    acc[1]);
      acc[2] = fmaf(ex, h2f(u.y & 0xffff), acc[2]);
      acc[3] = fmaf(ex, h2f(u.y >> 16),    acc[3]);
      acc[4] = fmaf(ex, h2f(u.z & 0xffff), acc[4]);
      acc[5] = fmaf(ex, h2f(u.z >> 16),    acc[5]);
      acc[6] = fmaf(ex, h2f(u.w & 0xffff), acc[6]);
      acc[7] = fmaf(ex, h2f(u.w >> 16),    acc[7]);
    }
  }
  // combine split-K halves (partner lane t^4, same node, same wave)
#pragma unroll
  for (int j = 0; j < 8; j++) acc[j] += __shfl_xor(acc[j], 4);
  ssum += __shfl_xor(ssum, 4);
  if (n < N) {
    float inv = 1.0f / (ssum + 1e-16f);
    float4 bv = ((const float4*)b1)[cq * 2 + half];
    int ch0 = cq * 8 + half * 4;
    const float* A = acc + half * 4;
    x1t[nl][ch0 + 0] = fmaxf(fmaf(A[0], inv, bv.x), 0.f);
    x1t[nl][ch0 + 1] = fmaxf(fmaf(A[1], inv, bv.y), 0.f);
    x1t[nl][ch0 + 2] = fmaxf(fmaf(A[2], inv, bv.z), 0.f);
    x1t[nl][ch0 + 3] = fmaxf(fmaf(A[3], inv, bv.w), 0.f);
  }
  __syncthreads();
  // gemm2: 8 threads/node, 5 out-channels each
  float acc2[5] = {0, 0, 0, 0, 0};
  int cb = r * 5;
  if (n < N) {
    for (int k = 0; k < 32; k++) {
      float x = x1t[nl][k];
#pragma unroll
      for (int c = 0; c < 5; c++)
        acc2[c] = fmaf(x, Wl[k * 40 + cb + c], acc2[c]);
    }
    float ss = 0.f, sd = 0.f;
#pragma unroll
    for (int c = 0; c < 5; c++) {
      ss = fmaf(acc2[c], As2l[cb + c], ss);
      sd = fmaf(acc2[c], Ad2l[cb + c], sd);
    }
#pragma unroll
    for (int off = 1; off < 8; off <<= 1) {
      ss += __shfl_xor(ss, off);
      sd += __shfl_xor(sd, off);
    }
    if (r == 0) { as2[n] = ss; ad2[n] = sd; }
#pragma unroll
    for (int c = 0; c < 5; c++) h2r[nl][cb + c] = acc2[c];
  }
  __syncthreads();
  if (n < N && r < 5) {
    const float* hr = h2r[nl] + r * 8;
    uint4 u;
    u.x = (unsigned)f2h(hr[0]) | ((unsigned)f2h(hr[1]) << 16);
    u.y = (unsigned)f2h(hr[2]) | ((unsigned)f2h(hr[3]) << 16);
    u.z = (unsigned)f2h(hr[4]) | ((unsigned)f2h(hr[5]) << 16);
    u.w = (unsigned)f2h(hr[6]) | ((unsigned)f2h(hr[7]) << 16);
    h2h[(size_t)n * 8 + r] = u;  // 128B row stride, 80B used
  }
}

// ---------------- fused softmax+agg, layer 2 (split-K, LDS combine) ---------
__global__ __launch_bounds__(256) void agg2_fused(const int* __restrict__ rp,
                                                  const int* __restrict__ csr,
                                                  const float* __restrict__ as,
                                                  const float* __restrict__ ad,
                                                  const uint4* __restrict__ h2h,
                                                  const float* __restrict__ bias,
                                                  float* __restrict__ outp, int N) {
  __shared__ float part[256][9];
  int t = threadIdx.x;
  int idx = blockIdx.x * A2B + t;
  bool act = (t < A2B) && (idx < N * 10);
  int n = 0, half = 0, cq = 0, p0 = 0, p1 = 0;
  float adv = 0.f;
  if (act) {
    n = idx / 10;
    int r = idx % 10;
    half = r >= 5;
    cq = r - half * 5;
    p0 = rp[n]; p1 = rp[n + 1];
    adv = ad[n];
  }
  float acc[8] = {0, 0, 0, 0, 0, 0, 0, 0};
  float ssum = 0.f;
  if (act) {
    int p = p0 + half;
    for (; p + 2 < p1; p += 4) {
      int s0 = csr[p], s1 = csr[p + 2];
      float e0 = as[s0] + adv;
      float e1 = as[s1] + adv;
      uint4 u0 = h2h[(size_t)s0 * 8 + cq];
      uint4 u1 = h2h[(size_t)s1 * 8 + cq];
      e0 = e0 > 0.f ? e0 : 0.2f * e0;
      e1 = e1 > 0.f ? e1 : 0.2f * e1;
      float x0 = __expf(e0), x1e = __expf(e1);
      ssum += x0 + x1e;
      acc[0] = fmaf(x0, h2f(u0.x & 0xffff), acc[0]);
      acc[1] = fmaf(x0, h2f(u0.x >> 16),    acc[1]);
      acc[2] = fmaf(x0, h2f(u0.y & 0xffff), acc[2]);
      acc[3] = fmaf(x0, h2f(u0.y >> 16),    acc[3]);
      acc[4] = fmaf(x0, h2f(u0.z & 0xffff), acc[4]);
      acc[5] = fmaf(x0, h2f(u0.z >> 16),    acc[5]);
      acc[6] = fmaf(x0, h2f(u0.w & 0xffff), acc[6]);
      acc[7] = fmaf(x0, h2f(u0.w >> 16),    acc[7]);
      acc[0] = fmaf(x1e, h2f(u1.x & 0xffff), acc[0]);
      acc[1] = fmaf(x1e, h2f(u1.x >> 16),    acc[1]);
      acc[2] = fmaf(x1e, h2f(u1.y & 0xffff), acc[2]);
      acc[3] = fmaf(x1e, h2f(u1.y >> 16),    acc[3]);
      acc[4] = fmaf(x1e, h2f(u1.z & 0xffff), acc[4]);
      acc[5] = fmaf(x1e, h2f(u1.z >> 16),    acc[5]);
      acc[6] = fmaf(x1e, h2f(u1.w & 0xffff), acc[6]);
      acc[7] = fmaf(x1e, h2f(u1.w >> 16),    acc[7]);
    }
    for (; p < p1; p += 2) {
      int s = csr[p];
      float e = as[s] + adv;
      uint4 u = h2h[(size_t)s * 8 + cq];
      e = e > 0.f ? e : 0.2f * e;
      float ex = __expf(e);
      ssum += ex;
      acc[0] = fmaf(ex, h2f(u.x & 0xffff), acc[0]);
      acc[1] = fmaf(ex, h2f(u.x >> 16),    acc[1]);
      acc[2] = fmaf(ex, h2f(u.y & 0xffff), acc[2]);
      acc[3] = fmaf(ex, h2f(u.y >> 16),    acc[3]);
      acc[4] = fmaf(ex, h2f(u.z & 0xffff), acc[4]);
      acc[5] = fmaf(ex, h2f(u.z >> 16),    acc[5]);
      acc[6] = fmaf(ex, h2f(u.w & 0xffff), acc[6]);
      acc[7] = fmaf(ex, h2f(u.w >> 16),    acc[7]);
    }
  }
  if (act && half) {
#pragma unroll
    for (int j = 0; j < 8; j++) part[t][j] = acc[j];
    part[t][8] = ssum;
  }
  __syncthreads();
  if (act && !half) {
#pragma unroll
    for (int j = 0; j < 8; j++) acc[j] += part[t + 5][j];
    ssum += part[t + 5][8];
    float inv = 1.0f / (ssum + 1e-16f);
    const float4* b4 = (const float4*)bias;
    float4 ba = b4[cq * 2], bb = b4[cq * 2 + 1];
    float4 r0, r1;
    r0.x = fmaf(acc[0], inv, ba.x);
    r0.y = fmaf(acc[1], inv, ba.y);
    r0.z = fmaf(acc[2], inv, ba.z);
    r0.w = fmaf(acc[3], inv, ba.w);
    r1.x = fmaf(acc[4], inv, bb.x);
    r1.y = fmaf(acc[5], inv, bb.y);
    r1.z = fmaf(acc[6], inv, bb.z);
    r1.w = fmaf(acc[7], inv, bb.w);
    ((float4*)outp)[(size_t)n * 10 + cq * 2]     = r0;
    ((float4*)outp)[(size_t)n * 10 + cq * 2 + 1] = r1;
  }
}

// ---------------- host launcher ----------------
extern "C" void kernel_launch(void* const* d_in, const int* in_sizes, int n_in,
                              void* d_out, int out_size, void* d_ws, size_t ws_size,
                              hipStream_t stream) {
  const float* X    = (const float*)d_in[0];
  const long long* eg64 = (const long long*)d_in[1];
  const int* eg32   = (const int*)d_in[1];
  const float* W1   = (const float*)d_in[3];
  const float* as1w = (const float*)d_in[4];
  const float* ad1w = (const float*)d_in[5];
  const float* b1   = (const float*)d_in[6];
  const float* W2   = (const float*)d_in[7];
  const float* as2w = (const float*)d_in[8];
  const float* ad2w = (const float*)d_in[9];
  const float* b2   = (const float*)d_in[10];
  float* out = (float*)d_out;

  const int N  = in_sizes[0] / 128;
  const int E  = in_sizes[1] / 2;
  const int EN = E + N;
  const int NB2 = (N + CB_SZ - 1) / CB_SZ;
  const int NWG = (EN + CHUNK - 1) / CHUNK;
  const int NH  = NB2 * NWG;

  char* wbase = (char*)d_ws;
  size_t off = 0;
  auto alloc = [&](size_t bytes) -> void* {
    void* p = wbase + off;
    off += (bytes + 255) & ~(size_t)255;
    return p;
  };

  uint4* h1h = (uint4*)alloc((size_t)N * 64);        // fp16 h1, 64B rows
  uint4* h2h = (uint4*)alloc((size_t)N * 128);       // fp16 h2, 128B padded rows
  float* as1 = (float*)alloc((size_t)N * 2 * 4);
  float* ad1 = (float*)alloc((size_t)N * 2 * 4);
  float* as2 = (float*)alloc((size_t)N * 4);
  float* ad2 = (float*)alloc((size_t)N * 4);
  int* rp     = (int*)alloc((size_t)(N + 1) * 4);
  int* histg  = (int*)alloc((size_t)NH * 4);
  int* hists  = (int*)alloc((size_t)(NH + 1) * 4);
  int* bsum   = (int*)alloc(1024 * 4);
  int* boff   = (int*)alloc(1024 * 4);
  int* csr    = (int*)alloc((size_t)EN * 4);
  int* tmp    = (int*)alloc((size_t)EN * 4);
  (void)ws_size; (void)n_in; (void)out_size;

  const int gN  = (N + 255) / 256;
  const int nbH = (NH + 1023) / 1024;

  // CSR build (atomic-free; is64 detected per-WG, block-uniform)
  chunk_hist<<<NWG, 256, 0, stream>>>(eg64, eg32, E, N, NWG, histg);
  scan_blocks<<<nbH, 1024, 0, stream>>>(histg, hists, bsum, NH);
  scan_sums<<<1, 64, 0, stream>>>(bsum, boff, nbH);
  scan_add<<<nbH, 1024, 0, stream>>>(hists, boff, NH, EN);
  chunk_scatter<<<NWG, 256, 0, stream>>>(eg64, eg32, E, N, NWG, hists, tmp);
  bucket_rp_sort<<<NB2, 256, 0, stream>>>(hists, NWG, tmp, rp, csr, N, EN);

  // Layer 1 projection
  gemm1f<<<gN, 256, 0, stream>>>(X, W1, as1w, ad1w, h1h, as1, ad1, N);
  // agg1 + gemm2 + attn2 fused (x1 never touches global)
  agg1_gemm2<<<(N + 31) / 32, 256, 0, stream>>>(rp, csr, as1, ad1, h1h, b1,
                                                W2, as2w, ad2w, h2h, as2, ad2, N);
  // Layer 2 aggregation -> output
  agg2_fused<<<(N * 10 + A2B - 1) / A2B, 256, 0, stream>>>(rp, csr, as2, ad2,
                                                           h2h, b2, out, N);
}

// Round 9
// 378.005 us; speedup vs baseline: 1.0749x; 1.0749x over previous
//
#include <hip/hip_runtime.h>

// GAT 2-layer forward on MI355X.
// Round 9: r8 regressed because CHUNK 4096 / CB_SZ 256 shrank scatter runs to
// ~10 entries (42B < 1 cache line) -> write amp 72MB/13MB (r1 disease back).
// Revert build geometry to r6's proven CHUNK 8192 / CB_SZ 512 (42-entry/168B
// runs), keep r8's wins: block-uniform detect64, agg1+gemm2+attn2 fusion,
// 9 dispatches. Payloads: h1h fp16 64B rows, h2h fp16 128B-padded rows.

#define DEVFN __device__ __forceinline__
#define CB_SHIFT 9
#define CB_SZ 512
#define CHUNK 8192
#define A2B 250  // agg2 active threads per block (multiple of 10)

DEVFN unsigned short f2h(float f) {
  _Float16 h = (_Float16)f;
  unsigned short u;
  __builtin_memcpy(&u, &h, 2);
  return u;
}
DEVFN float h2f(unsigned short u) {
  _Float16 h;
  __builtin_memcpy(&h, &u, 2);
  return (float)h;
}

DEVFN void read_edge(const long long* eg64, const int* eg32, int is64, int E,
                     int i, int& s, int& d) {
  if (i >= E) { s = d = i - E; return; }
  if (is64) { s = (int)eg64[i]; d = (int)eg64[E + i]; }
  else      { s = eg32[i];      d = eg32[E + i]; }
}

// block-uniform edge dtype detection: EVERY wave samples the same 64 in-range
// indices (int64 data => high words all zero; int32 data => random src values).
DEVFN int detect64(const int* eg32, int E, int i0, int t) {
  int base = i0;
  if (base > E - 64) base = E - 64;
  if (base < 0) base = 0;
  int i = base + (t & 63);
  unsigned long long m = __ballot((i < E) && (eg32[2 * i + 1] != 0));
  return m == 0ull;
}

// ---------------- generic scan (blocks of 1024) for chunk histograms --------
__global__ void scan_blocks(const int* __restrict__ cnt, int* __restrict__ rp,
                            int* __restrict__ bsum, int n) {
  __shared__ int buf[2][1024];
  int t = threadIdx.x;
  int gid = blockIdx.x * 1024 + t;
  int v = (gid < n) ? cnt[gid] : 0;
  buf[0][t] = v;
  __syncthreads();
  int pin = 0;
  for (int offd = 1; offd < 1024; offd <<= 1) {
    int nv = buf[pin][t];
    if (t >= offd) nv += buf[pin][t - offd];
    buf[1 - pin][t] = nv;
    pin = 1 - pin;
    __syncthreads();
  }
  int inc = buf[pin][t];
  if (gid < n) rp[gid] = inc - v;  // exclusive within block
  if (t == 1023) bsum[blockIdx.x] = inc;
}

__global__ void scan_sums(const int* bsum, int* boff, int nb) {
  if (blockIdx.x == 0 && threadIdx.x == 0) {
    int r = 0;
    for (int i = 0; i < nb; i++) { boff[i] = r; r += bsum[i]; }
  }
}

__global__ void scan_add(int* rp, const int* boff, int n, int total) {
  int i = blockIdx.x * 1024 + threadIdx.x;
  if (i < n) rp[i] = rp[i] + boff[blockIdx.x];
  if (i == 0) rp[n] = total;
}

// ---------------- CSR build (atomic-free multisplit) ----------------
__global__ __launch_bounds__(256) void chunk_hist(const long long* eg64,
                                                  const int* eg32,
                                                  int E, int N, int NWG,
                                                  int* __restrict__ histg) {
  __shared__ int lh[CB_SZ];
  int w = blockIdx.x, t = threadIdx.x;
  int NB2 = (N + CB_SZ - 1) / CB_SZ;
  for (int j = t; j < NB2; j += 256) lh[j] = 0;
  int i0 = w * CHUNK;
  int is64 = detect64(eg32, E, i0, t);
  __syncthreads();
  int EN = E + N;
  int i1 = i0 + CHUNK; if (i1 > EN) i1 = EN;
  for (int i = i0 + t; i < i1; i += 256) {
    int d;
    if (i >= E) d = i - E;
    else d = is64 ? (int)eg64[E + i] : eg32[E + i];
    atomicAdd(&lh[d >> CB_SHIFT], 1);
  }
  __syncthreads();
  for (int b = t; b < NB2; b += 256) histg[b * NWG + w] = lh[b];
}

__global__ __launch_bounds__(256) void chunk_scatter(const long long* eg64,
                                                     const int* eg32,
                                                     int E, int N, int NWG,
                                                     const int* __restrict__ hists,
                                                     int* __restrict__ tmp) {
  __shared__ int lcur[CB_SZ];
  int w = blockIdx.x, t = threadIdx.x;
  int NB2 = (N + CB_SZ - 1) / CB_SZ;
  for (int b = t; b < NB2; b += 256) lcur[b] = hists[b * NWG + w];
  int i0 = w * CHUNK;
  int is64 = detect64(eg32, E, i0, t);
  __syncthreads();
  int EN = E + N;
  int i1 = i0 + CHUNK; if (i1 > EN) i1 = EN;
  for (int i = i0 + t; i < i1; i += 256) {
    int s, d;
    read_edge(eg64, eg32, is64, E, i, s, d);
    int b = d >> CB_SHIFT;
    int pos = atomicAdd(&lcur[b], 1);
    tmp[pos] = (s << CB_SHIFT) | (d & (CB_SZ - 1));
  }
}

// per-bucket (512 nodes): counts + in-LDS scan -> rp; scatter tmp -> csr
__global__ __launch_bounds__(256) void bucket_rp_sort(const int* __restrict__ hists,
                                                      int NWG,
                                                      const int* __restrict__ tmp,
                                                      int* __restrict__ rp,
                                                      int* __restrict__ csr,
                                                      int N, int EN) {
  __shared__ int lc[CB_SZ];
  __shared__ int ps[256];
  __shared__ int lcur[CB_SZ];
  int b = blockIdx.x, t = threadIdx.x;
  for (int j = t; j < CB_SZ; j += 256) lc[j] = 0;
  __syncthreads();
  int w0 = hists[b * NWG];
  int w1 = hists[(b + 1) * NWG];  // last bucket reads hists[NB2*NWG] == EN
  for (int p = w0 + t; p < w1; p += 256)
    atomicAdd(&lc[tmp[p] & (CB_SZ - 1)], 1);
  __syncthreads();
  int a = lc[2 * t], c = lc[2 * t + 1];
  ps[t] = a + c;
  __syncthreads();
  for (int off = 1; off < 256; off <<= 1) {
    int v = ps[t];
    int u = (t >= off) ? ps[t - off] : 0;
    __syncthreads();
    ps[t] = v + u;
    __syncthreads();
  }
  int base = w0 + ps[t] - (a + c);  // exclusive prefix within bucket
  lcur[2 * t] = base;
  lcur[2 * t + 1] = base + a;
  int n0 = b * CB_SZ;
  if (n0 + 2 * t < N) rp[n0 + 2 * t] = base;
  if (n0 + 2 * t + 1 < N) rp[n0 + 2 * t + 1] = base + a;
  if (b == (int)gridDim.x - 1 && t == 0) rp[N] = EN;
  __syncthreads();
  for (int p = w0 + t; p < w1; p += 256) {
    int e = tmp[p];
    int pos = atomicAdd(&lcur[e & (CB_SZ - 1)], 1);
    csr[pos] = e >> CB_SHIFT;
  }
}

// ---------------- fused GEMM + attn + fp16 pack, layer 1 ----------------
__global__ __launch_bounds__(256) void gemm1f(const float* __restrict__ X,
                                              const float* __restrict__ W,
                                              const float* __restrict__ att_s,
                                              const float* __restrict__ att_d,
                                              uint4* __restrict__ h1h,
                                              float* __restrict__ as1,
                                              float* __restrict__ ad1, int N) {
  __shared__ float Wl[128 * 32];
  __shared__ float Asl[32], Adl[32];
  int t = threadIdx.x;
  for (int i = t; i < 1024; i += 256)
    ((float4*)Wl)[i] = ((const float4*)W)[i];
  if (t < 32) { Asl[t] = att_s[t]; Adl[t] = att_d[t]; }
  __syncthreads();
  int n = blockIdx.x * 256 + t;
  if (n >= N) return;
  const float4* X4 = (const float4*)(X + (size_t)n * 128);
  float acc[32];
#pragma unroll
  for (int c = 0; c < 32; c++) acc[c] = 0.f;
  for (int k4 = 0; k4 < 32; k4++) {
    float4 x = X4[k4];
    const float4* w4 = (const float4*)(Wl + k4 * 128);
#pragma unroll
    for (int c4 = 0; c4 < 8; c4++) {
      float4 w0 = w4[c4], w1 = w4[8 + c4], w2 = w4[16 + c4], w3 = w4[24 + c4];
      float* A = acc + c4 * 4;
      A[0] = fmaf(x.x, w0.x, A[0]); A[1] = fmaf(x.x, w0.y, A[1]);
      A[2] = fmaf(x.x, w0.z, A[2]); A[3] = fmaf(x.x, w0.w, A[3]);
      A[0] = fmaf(x.y, w1.x, A[0]); A[1] = fmaf(x.y, w1.y, A[1]);
      A[2] = fmaf(x.y, w1.z, A[2]); A[3] = fmaf(x.y, w1.w, A[3]);
      A[0] = fmaf(x.z, w2.x, A[0]); A[1] = fmaf(x.z, w2.y, A[1]);
      A[2] = fmaf(x.z, w2.z, A[2]); A[3] = fmaf(x.z, w2.w, A[3]);
      A[0] = fmaf(x.w, w3.x, A[0]); A[1] = fmaf(x.w, w3.y, A[1]);
      A[2] = fmaf(x.w, w3.z, A[2]); A[3] = fmaf(x.w, w3.w, A[3]);
    }
  }
  float s0 = 0.f, d0 = 0.f, s1 = 0.f, d1 = 0.f;
#pragma unroll
  for (int c = 0; c < 16; c++) {
    s0 = fmaf(acc[c], Asl[c], s0);
    d0 = fmaf(acc[c], Adl[c], d0);
    s1 = fmaf(acc[16 + c], Asl[16 + c], s1);
    d1 = fmaf(acc[16 + c], Adl[16 + c], d1);
  }
  as1[n * 2] = s0; as1[n * 2 + 1] = s1;
  ad1[n * 2] = d0; ad1[n * 2 + 1] = d1;
#pragma unroll
  for (int j = 0; j < 4; j++) {
    uint4 u;
    u.x = (unsigned)f2h(acc[j * 8 + 0]) | ((unsigned)f2h(acc[j * 8 + 1]) << 16);
    u.y = (unsigned)f2h(acc[j * 8 + 2]) | ((unsigned)f2h(acc[j * 8 + 3]) << 16);
    u.z = (unsigned)f2h(acc[j * 8 + 4]) | ((unsigned)f2h(acc[j * 8 + 5]) << 16);
    u.w = (unsigned)f2h(acc[j * 8 + 6]) | ((unsigned)f2h(acc[j * 8 + 7]) << 16);
    h1h[(size_t)n * 4 + j] = u;
  }
}

// ------- fused agg1 (split-K, shfl) + gemm2 + attn2 + fp16 pack -------------
// block = 32 nodes x 8 threads; r=(half,cq); x1 row lives only in LDS.
__global__ __launch_bounds__(256) void agg1_gemm2(
    const int* __restrict__ rp, const int* __restrict__ csr,
    const float* __restrict__ as, const float* __restrict__ ad,
    const uint4* __restrict__ h1h, const float* __restrict__ b1,
    const float* __restrict__ W2, const float* __restrict__ as2w,
    const float* __restrict__ ad2w, uint4* __restrict__ h2h,
    float* __restrict__ as2, float* __restrict__ ad2, int N) {
  __shared__ float Wl[32 * 40];
  __shared__ float As2l[40], Ad2l[40];
  __shared__ float x1t[32][33];
  __shared__ float h2r[32][41];
  int t = threadIdx.x;
  for (int i = t; i < 320; i += 256)
    ((float4*)Wl)[i] = ((const float4*)W2)[i];
  if (t < 40) { As2l[t] = as2w[t]; Ad2l[t] = ad2w[t]; }
  int nl = t >> 3, r = t & 7;
  int half = r >> 2, cq = r & 3;
  int h = cq >> 1;
  int n = blockIdx.x * 32 + nl;
  float acc[8] = {0, 0, 0, 0, 0, 0, 0, 0};
  float ssum = 0.f;
  if (n < N) {
    int p0 = rp[n], p1 = rp[n + 1];
    float adv = ad[n * 2 + h];
    int p = p0 + half;
    for (; p + 2 < p1; p += 4) {
      int s0 = csr[p], s1 = csr[p + 2];
      float e0 = as[s0 * 2 + h] + adv;
      float e1 = as[s1 * 2 + h] + adv;
      uint4 u0 = h1h[(size_t)s0 * 4 + cq];
      uint4 u1 = h1h[(size_t)s1 * 4 + cq];
      e0 = e0 > 0.f ? e0 : 0.2f * e0;
      e1 = e1 > 0.f ? e1 : 0.2f * e1;
      float x0 = __expf(e0), x1e = __expf(e1);
      ssum += x0 + x1e;
      acc[0] = fmaf(x0, h2f(u0.x & 0xffff), acc[0]);
      acc[1] = fmaf(x0, h2f(u0.x >> 16),    acc[1]);
      acc[2] = fmaf(x0, h2f(u0.y & 0xffff), acc[2]);
      acc[3] = fmaf(x0, h2f(u0.y >> 16),    acc[3]);
      acc[4] = fmaf(x0, h2f(u0.z & 0xffff), acc[4]);
      acc[5] = fmaf(x0, h2f(u0.z >> 16),    acc[5]);
      acc[6] = fmaf(x0, h2f(u0.w & 0xffff), acc[6]);
      acc[7] = fmaf(x0, h2f(u0.w >> 16),    acc[7]);
      acc[0] = fmaf(x1e, h2f(u1.x & 0xffff), acc[0]);
      acc[1] = fmaf(x1e, h2f(u1.x >> 16),    acc[1]);
      acc[2] = fmaf(x1e, h2f(u1.y & 0xffff), acc[2]);
      acc[3] = fmaf(x1e, h2f(u1.y >> 16),    acc[3]);
      acc[4] = fmaf(x1e, h2f(u1.z & 0xffff), acc[4]);
      acc[5] = fmaf(x1e, h2f(u1.z >> 16),    acc[5]);
      acc[6] = fmaf(x1e, h2f(u1.w & 0xffff), acc[6]);
      acc[7] = fmaf(x1e, h2f(u1.w >> 16),    acc[7]);
    }
    for (; p < p1; p += 2) {
      int s = csr[p];
      float e = as[s * 2 + h] + adv;
      uint4 u = h1h[(size_t)s * 4 + cq];
      e = e > 0.f ? e : 0.2f * e;
      float ex = __expf(e);
      ssum += ex;
      acc[0] = fmaf(ex, h2f(u.x & 0xffff), acc[0]);
      acc[1] = fmaf(ex, h2f(u.x >> 16),    acc[1]);
      acc[2] = fmaf(ex, h2f(u.y & 0xffff), acc[2]);
      acc[3] = fmaf(ex, h2f(u.y >> 16),    acc[3]);
      acc[4] = fmaf(ex, h2f(u.z & 0xffff), acc[4]);
      acc[5] = fmaf(ex, h2f(u.z >> 16),    acc[5]);
      acc[6] = fmaf(ex, h2f(u.w & 0xffff), acc[6]);
      acc[7] = fmaf(ex, h2f(u.w >> 16),    acc[7]);
    }
  }
  // combine split-K halves (partner lane t^4, same node, same wave)
#pragma unroll
  for (int j = 0; j < 8; j++) acc[j] += __shfl_xor(acc[j], 4);
  ssum += __shfl_xor(ssum, 4);
  if (n < N) {
    float inv = 1.0f / (ssum + 1e-16f);
    float4 bv = ((const float4*)b1)[cq * 2 + half];
    int ch0 = cq * 8 + half * 4;
    const float* A = acc + half * 4;
    x1t[nl][ch0 + 0] = fmaxf(fmaf(A[0], inv, bv.x), 0.f);
    x1t[nl][ch0 + 1] = fmaxf(fmaf(A[1], inv, bv.y), 0.f);
    x1t[nl][ch0 + 2] = fmaxf(fmaf(A[2], inv, bv.z), 0.f);
    x1t[nl][ch0 + 3] = fmaxf(fmaf(A[3], inv, bv.w), 0.f);
  }
  __syncthreads();
  // gemm2: 8 threads/node, 5 out-channels each
  float acc2[5] = {0, 0, 0, 0, 0};
  int cb = r * 5;
  if (n < N) {
    for (int k = 0; k < 32; k++) {
      float x = x1t[nl][k];
#pragma unroll
      for (int c = 0; c < 5; c++)
        acc2[c] = fmaf(x, Wl[k * 40 + cb + c], acc2[c]);
    }
    float ss = 0.f, sd = 0.f;
#pragma unroll
    for (int c = 0; c < 5; c++) {
      ss = fmaf(acc2[c], As2l[cb + c], ss);
      sd = fmaf(acc2[c], Ad2l[cb + c], sd);
    }
#pragma unroll
    for (int off = 1; off < 8; off <<= 1) {
      ss += __shfl_xor(ss, off);
      sd += __shfl_xor(sd, off);
    }
    if (r == 0) { as2[n] = ss; ad2[n] = sd; }
#pragma unroll
    for (int c = 0; c < 5; c++) h2r[nl][cb + c] = acc2[c];
  }
  __syncthreads();
  if (n < N && r < 5) {
    const float* hr = h2r[nl] + r * 8;
    uint4 u;
    u.x = (unsigned)f2h(hr[0]) | ((unsigned)f2h(hr[1]) << 16);
    u.y = (unsigned)f2h(hr[2]) | ((unsigned)f2h(hr[3]) << 16);
    u.z = (unsigned)f2h(hr[4]) | ((unsigned)f2h(hr[5]) << 16);
    u.w = (unsigned)f2h(hr[6]) | ((unsigned)f2h(hr[7]) << 16);
    h2h[(size_t)n * 8 + r] = u;  // 128B row stride, 80B used
  }
}

// ---------------- fused softmax+agg, layer 2 (split-K, LDS combine) ---------
__global__ __launch_bounds__(256) void agg2_fused(const int* __restrict__ rp,
                                                  const int* __restrict__ csr,
                                                  const float* __restrict__ as,
                                                  const float* __restrict__ ad,
                                                  const uint4* __restrict__ h2h,
                                                  const float* __restrict__ bias,
                                                  float* __restrict__ outp, int N) {
  __shared__ float part[256][9];
  int t = threadIdx.x;
  int idx = blockIdx.x * A2B + t;
  bool act = (t < A2B) && (idx < N * 10);
  int n = 0, half = 0, cq = 0, p0 = 0, p1 = 0;
  float adv = 0.f;
  if (act) {
    n = idx / 10;
    int r = idx % 10;
    half = r >= 5;
    cq = r - half * 5;
    p0 = rp[n]; p1 = rp[n + 1];
    adv = ad[n];
  }
  float acc[8] = {0, 0, 0, 0, 0, 0, 0, 0};
  float ssum = 0.f;
  if (act) {
    int p = p0 + half;
    for (; p + 2 < p1; p += 4) {
      int s0 = csr[p], s1 = csr[p + 2];
      float e0 = as[s0] + adv;
      float e1 = as[s1] + adv;
      uint4 u0 = h2h[(size_t)s0 * 8 + cq];
      uint4 u1 = h2h[(size_t)s1 * 8 + cq];
      e0 = e0 > 0.f ? e0 : 0.2f * e0;
      e1 = e1 > 0.f ? e1 : 0.2f * e1;
      float x0 = __expf(e0), x1e = __expf(e1);
      ssum += x0 + x1e;
      acc[0] = fmaf(x0, h2f(u0.x & 0xffff), acc[0]);
      acc[1] = fmaf(x0, h2f(u0.x >> 16),    acc[1]);
      acc[2] = fmaf(x0, h2f(u0.y & 0xffff), acc[2]);
      acc[3] = fmaf(x0, h2f(u0.y >> 16),    acc[3]);
      acc[4] = fmaf(x0, h2f(u0.z & 0xffff), acc[4]);
      acc[5] = fmaf(x0, h2f(u0.z >> 16),    acc[5]);
      acc[6] = fmaf(x0, h2f(u0.w & 0xffff), acc[6]);
      acc[7] = fmaf(x0, h2f(u0.w >> 16),    acc[7]);
      acc[0] = fmaf(x1e, h2f(u1.x & 0xffff), acc[0]);
      acc[1] = fmaf(x1e, h2f(u1.x >> 16),    acc[1]);
      acc[2] = fmaf(x1e, h2f(u1.y & 0xffff), acc[2]);
      acc[3] = fmaf(x1e, h2f(u1.y >> 16),    acc[3]);
      acc[4] = fmaf(x1e, h2f(u1.z & 0xffff), acc[4]);
      acc[5] = fmaf(x1e, h2f(u1.z >> 16),    acc[5]);
      acc[6] = fmaf(x1e, h2f(u1.w & 0xffff), acc[6]);
      acc[7] = fmaf(x1e, h2f(u1.w >> 16),    acc[7]);
    }
    for (; p < p1; p += 2) {
      int s = csr[p];
      float e = as[s] + adv;
      uint4 u = h2h[(size_t)s * 8 + cq];
      e = e > 0.f ? e : 0.2f * e;
      float ex = __expf(e);
      ssum += ex;
      acc[0] = fmaf(ex, h2f(u.x & 0xffff), acc[0]);
      acc[1] = fmaf(ex, h2f(u.x >> 16),    acc[1]);
      acc[2] = fmaf(ex, h2f(u.y & 0xffff), acc[2]);
      acc[3] = fmaf(ex, h2f(u.y >> 16),    acc[3]);
      acc[4] = fmaf(ex, h2f(u.z & 0xffff), acc[4]);
      acc[5] = fmaf(ex, h2f(u.z >> 16),    acc[5]);
      acc[6] = fmaf(ex, h2f(u.w & 0xffff), acc[6]);
      acc[7] = fmaf(ex, h2f(u.w >> 16),    acc[7]);
    }
  }
  if (act && half) {
#pragma unroll
    for (int j = 0; j < 8; j++) part[t][j] = acc[j];
    part[t][8] = ssum;
  }
  __syncthreads();
  if (act && !half) {
#pragma unroll
    for (int j = 0; j < 8; j++) acc[j] += part[t + 5][j];
    ssum += part[t + 5][8];
    float inv = 1.0f / (ssum + 1e-16f);
    const float4* b4 = (const float4*)bias;
    float4 ba = b4[cq * 2], bb = b4[cq * 2 + 1];
    float4 r0, r1;
    r0.x = fmaf(acc[0], inv, ba.x);
    r0.y = fmaf(acc[1], inv, ba.y);
    r0.z = fmaf(acc[2], inv, ba.z);
    r0.w = fmaf(acc[3], inv, ba.w);
    r1.x = fmaf(acc[4], inv, bb.x);
    r1.y = fmaf(acc[5], inv, bb.y);
    r1.z = fmaf(acc[6], inv, bb.z);
    r1.w = fmaf(acc[7], inv, bb.w);
    ((float4*)outp)[(size_t)n * 10 + cq * 2]     = r0;
    ((float4*)outp)[(size_t)n * 10 + cq * 2 + 1] = r1;
  }
}

// ---------------- host launcher ----------------
extern "C" void kernel_launch(void* const* d_in, const int* in_sizes, int n_in,
                              void* d_out, int out_size, void* d_ws, size_t ws_size,
                              hipStream_t stream) {
  const float* X    = (const float*)d_in[0];
  const long long* eg64 = (const long long*)d_in[1];
  const int* eg32   = (const int*)d_in[1];
  const float* W1   = (const float*)d_in[3];
  const float* as1w = (const float*)d_in[4];
  const float* ad1w = (const float*)d_in[5];
  const float* b1   = (const float*)d_in[6];
  const float* W2   = (const float*)d_in[7];
  const float* as2w = (const float*)d_in[8];
  const float* ad2w = (const float*)d_in[9];
  const float* b2   = (const float*)d_in[10];
  float* out = (float*)d_out;

  const int N  = in_sizes[0] / 128;
  const int E  = in_sizes[1] / 2;
  const int EN = E + N;
  const int NB2 = (N + CB_SZ - 1) / CB_SZ;
  const int NWG = (EN + CHUNK - 1) / CHUNK;
  const int NH  = NB2 * NWG;

  char* wbase = (char*)d_ws;
  size_t off = 0;
  auto alloc = [&](size_t bytes) -> void* {
    void* p = wbase + off;
    off += (bytes + 255) & ~(size_t)255;
    return p;
  };

  uint4* h1h = (uint4*)alloc((size_t)N * 64);        // fp16 h1, 64B rows
  uint4* h2h = (uint4*)alloc((size_t)N * 128);       // fp16 h2, 128B padded rows
  float* as1 = (float*)alloc((size_t)N * 2 * 4);
  float* ad1 = (float*)alloc((size_t)N * 2 * 4);
  float* as2 = (float*)alloc((size_t)N * 4);
  float* ad2 = (float*)alloc((size_t)N * 4);
  int* rp     = (int*)alloc((size_t)(N + 1) * 4);
  int* histg  = (int*)alloc((size_t)NH * 4);
  int* hists  = (int*)alloc((size_t)(NH + 1) * 4);
  int* bsum   = (int*)alloc(1024 * 4);
  int* boff   = (int*)alloc(1024 * 4);
  int* csr    = (int*)alloc((size_t)EN * 4);
  int* tmp    = (int*)alloc((size_t)EN * 4);
  (void)ws_size; (void)n_in; (void)out_size;

  const int gN  = (N + 255) / 256;
  const int nbH = (NH + 1023) / 1024;

  // CSR build (atomic-free; is64 detected per-WG, block-uniform)
  chunk_hist<<<NWG, 256, 0, stream>>>(eg64, eg32, E, N, NWG, histg);
  scan_blocks<<<nbH, 1024, 0, stream>>>(histg, hists, bsum, NH);
  scan_sums<<<1, 64, 0, stream>>>(bsum, boff, nbH);
  scan_add<<<nbH, 1024, 0, stream>>>(hists, boff, NH, EN);
  chunk_scatter<<<NWG, 256, 0, stream>>>(eg64, eg32, E, N, NWG, hists, tmp);
  bucket_rp_sort<<<NB2, 256, 0, stream>>>(hists, NWG, tmp, rp, csr, N, EN);

  // Layer 1 projection
  gemm1f<<<gN, 256, 0, stream>>>(X, W1, as1w, ad1w, h1h, as1, ad1, N);
  // agg1 + gemm2 + attn2 fused (x1 never touches global)
  agg1_gemm2<<<(N + 31) / 32, 256, 0, stream>>>(rp, csr, as1, ad1, h1h, b1,
                                                W2, as2w, ad2w, h2h, as2, ad2, N);
  // Layer 2 aggregation -> output
  agg2_fused<<<(N * 10 + A2B - 1) / A2B, 256, 0, stream>>>(rp, csr, as2, ad2,
                                                           h2h, b2, out, N);
}

// Round 10
// 370.780 us; speedup vs baseline: 1.0958x; 1.0195x over previous
//
#include <hip/hip_runtime.h>

// GAT 2-layer forward on MI355X.
// Round 10: split-K 2 -> 4 on both gather kernels (r9: agg2 occ 68%, VALU 28%,
// FETCH flat -- still latency headroom per the r5->r6 lesson).
//  - agg2: 20 thr/node (4 halves x 5 chunks), 240-active blocks, LDS combine.
//  - agg1 (in agg1_gemm2): 16 thr/node (4 halves x 4 chunks), shfl 4+8 combine.
// Build unchanged (r9 geometry: CHUNK 8192 / CB_SZ 512, block-uniform detect64).
// Payloads: h1h fp16 64B rows, h2h fp16 128B-padded rows. 9 dispatches.

#define DEVFN __device__ __forceinline__
#define CB_SHIFT 9
#define CB_SZ 512
#define CHUNK 8192
#define A2B 240  // agg2 active threads per block (12 nodes x 20)

DEVFN unsigned short f2h(float f) {
  _Float16 h = (_Float16)f;
  unsigned short u;
  __builtin_memcpy(&u, &h, 2);
  return u;
}
DEVFN float h2f(unsigned short u) {
  _Float16 h;
  __builtin_memcpy(&h, &u, 2);
  return (float)h;
}

DEVFN void read_edge(const long long* eg64, const int* eg32, int is64, int E,
                     int i, int& s, int& d) {
  if (i >= E) { s = d = i - E; return; }
  if (is64) { s = (int)eg64[i]; d = (int)eg64[E + i]; }
  else      { s = eg32[i];      d = eg32[E + i]; }
}

// block-uniform edge dtype detection: EVERY wave samples the same 64 in-range
// indices (int64 data => high words all zero; int32 data => random src values).
DEVFN int detect64(const int* eg32, int E, int i0, int t) {
  int base = i0;
  if (base > E - 64) base = E - 64;
  if (base < 0) base = 0;
  int i = base + (t & 63);
  unsigned long long m = __ballot((i < E) && (eg32[2 * i + 1] != 0));
  return m == 0ull;
}

// ---------------- generic scan (blocks of 1024) for chunk histograms --------
__global__ void scan_blocks(const int* __restrict__ cnt, int* __restrict__ rp,
                            int* __restrict__ bsum, int n) {
  __shared__ int buf[2][1024];
  int t = threadIdx.x;
  int gid = blockIdx.x * 1024 + t;
  int v = (gid < n) ? cnt[gid] : 0;
  buf[0][t] = v;
  __syncthreads();
  int pin = 0;
  for (int offd = 1; offd < 1024; offd <<= 1) {
    int nv = buf[pin][t];
    if (t >= offd) nv += buf[pin][t - offd];
    buf[1 - pin][t] = nv;
    pin = 1 - pin;
    __syncthreads();
  }
  int inc = buf[pin][t];
  if (gid < n) rp[gid] = inc - v;  // exclusive within block
  if (t == 1023) bsum[blockIdx.x] = inc;
}

__global__ void scan_sums(const int* bsum, int* boff, int nb) {
  if (blockIdx.x == 0 && threadIdx.x == 0) {
    int r = 0;
    for (int i = 0; i < nb; i++) { boff[i] = r; r += bsum[i]; }
  }
}

__global__ void scan_add(int* rp, const int* boff, int n, int total) {
  int i = blockIdx.x * 1024 + threadIdx.x;
  if (i < n) rp[i] = rp[i] + boff[blockIdx.x];
  if (i == 0) rp[n] = total;
}

// ---------------- CSR build (atomic-free multisplit) ----------------
__global__ __launch_bounds__(256) void chunk_hist(const long long* eg64,
                                                  const int* eg32,
                                                  int E, int N, int NWG,
                                                  int* __restrict__ histg) {
  __shared__ int lh[CB_SZ];
  int w = blockIdx.x, t = threadIdx.x;
  int NB2 = (N + CB_SZ - 1) / CB_SZ;
  for (int j = t; j < NB2; j += 256) lh[j] = 0;
  int i0 = w * CHUNK;
  int is64 = detect64(eg32, E, i0, t);
  __syncthreads();
  int EN = E + N;
  int i1 = i0 + CHUNK; if (i1 > EN) i1 = EN;
  for (int i = i0 + t; i < i1; i += 256) {
    int d;
    if (i >= E) d = i - E;
    else d = is64 ? (int)eg64[E + i] : eg32[E + i];
    atomicAdd(&lh[d >> CB_SHIFT], 1);
  }
  __syncthreads();
  for (int b = t; b < NB2; b += 256) histg[b * NWG + w] = lh[b];
}

__global__ __launch_bounds__(256) void chunk_scatter(const long long* eg64,
                                                     const int* eg32,
                                                     int E, int N, int NWG,
                                                     const int* __restrict__ hists,
                                                     int* __restrict__ tmp) {
  __shared__ int lcur[CB_SZ];
  int w = blockIdx.x, t = threadIdx.x;
  int NB2 = (N + CB_SZ - 1) / CB_SZ;
  for (int b = t; b < NB2; b += 256) lcur[b] = hists[b * NWG + w];
  int i0 = w * CHUNK;
  int is64 = detect64(eg32, E, i0, t);
  __syncthreads();
  int EN = E + N;
  int i1 = i0 + CHUNK; if (i1 > EN) i1 = EN;
  for (int i = i0 + t; i < i1; i += 256) {
    int s, d;
    read_edge(eg64, eg32, is64, E, i, s, d);
    int b = d >> CB_SHIFT;
    int pos = atomicAdd(&lcur[b], 1);
    tmp[pos] = (s << CB_SHIFT) | (d & (CB_SZ - 1));
  }
}

// per-bucket (512 nodes): counts + in-LDS scan -> rp; scatter tmp -> csr
__global__ __launch_bounds__(256) void bucket_rp_sort(const int* __restrict__ hists,
                                                      int NWG,
                                                      const int* __restrict__ tmp,
                                                      int* __restrict__ rp,
                                                      int* __restrict__ csr,
                                                      int N, int EN) {
  __shared__ int lc[CB_SZ];
  __shared__ int ps[256];
  __shared__ int lcur[CB_SZ];
  int b = blockIdx.x, t = threadIdx.x;
  for (int j = t; j < CB_SZ; j += 256) lc[j] = 0;
  __syncthreads();
  int w0 = hists[b * NWG];
  int w1 = hists[(b + 1) * NWG];  // last bucket reads hists[NB2*NWG] == EN
  for (int p = w0 + t; p < w1; p += 256)
    atomicAdd(&lc[tmp[p] & (CB_SZ - 1)], 1);
  __syncthreads();
  int a = lc[2 * t], c = lc[2 * t + 1];
  ps[t] = a + c;
  __syncthreads();
  for (int off = 1; off < 256; off <<= 1) {
    int v = ps[t];
    int u = (t >= off) ? ps[t - off] : 0;
    __syncthreads();
    ps[t] = v + u;
    __syncthreads();
  }
  int base = w0 + ps[t] - (a + c);  // exclusive prefix within bucket
  lcur[2 * t] = base;
  lcur[2 * t + 1] = base + a;
  int n0 = b * CB_SZ;
  if (n0 + 2 * t < N) rp[n0 + 2 * t] = base;
  if (n0 + 2 * t + 1 < N) rp[n0 + 2 * t + 1] = base + a;
  if (b == (int)gridDim.x - 1 && t == 0) rp[N] = EN;
  __syncthreads();
  for (int p = w0 + t; p < w1; p += 256) {
    int e = tmp[p];
    int pos = atomicAdd(&lcur[e & (CB_SZ - 1)], 1);
    csr[pos] = e >> CB_SHIFT;
  }
}

// ---------------- fused GEMM + attn + fp16 pack, layer 1 ----------------
__global__ __launch_bounds__(256) void gemm1f(const float* __restrict__ X,
                                              const float* __restrict__ W,
                                              const float* __restrict__ att_s,
                                              const float* __restrict__ att_d,
                                              uint4* __restrict__ h1h,
                                              float* __restrict__ as1,
                                              float* __restrict__ ad1, int N) {
  __shared__ float Wl[128 * 32];
  __shared__ float Asl[32], Adl[32];
  int t = threadIdx.x;
  for (int i = t; i < 1024; i += 256)
    ((float4*)Wl)[i] = ((const float4*)W)[i];
  if (t < 32) { Asl[t] = att_s[t]; Adl[t] = att_d[t]; }
  __syncthreads();
  int n = blockIdx.x * 256 + t;
  if (n >= N) return;
  const float4* X4 = (const float4*)(X + (size_t)n * 128);
  float acc[32];
#pragma unroll
  for (int c = 0; c < 32; c++) acc[c] = 0.f;
  for (int k4 = 0; k4 < 32; k4++) {
    float4 x = X4[k4];
    const float4* w4 = (const float4*)(Wl + k4 * 128);
#pragma unroll
    for (int c4 = 0; c4 < 8; c4++) {
      float4 w0 = w4[c4], w1 = w4[8 + c4], w2 = w4[16 + c4], w3 = w4[24 + c4];
      float* A = acc + c4 * 4;
      A[0] = fmaf(x.x, w0.x, A[0]); A[1] = fmaf(x.x, w0.y, A[1]);
      A[2] = fmaf(x.x, w0.z, A[2]); A[3] = fmaf(x.x, w0.w, A[3]);
      A[0] = fmaf(x.y, w1.x, A[0]); A[1] = fmaf(x.y, w1.y, A[1]);
      A[2] = fmaf(x.y, w1.z, A[2]); A[3] = fmaf(x.y, w1.w, A[3]);
      A[0] = fmaf(x.z, w2.x, A[0]); A[1] = fmaf(x.z, w2.y, A[1]);
      A[2] = fmaf(x.z, w2.z, A[2]); A[3] = fmaf(x.z, w2.w, A[3]);
      A[0] = fmaf(x.w, w3.x, A[0]); A[1] = fmaf(x.w, w3.y, A[1]);
      A[2] = fmaf(x.w, w3.z, A[2]); A[3] = fmaf(x.w, w3.w, A[3]);
    }
  }
  float s0 = 0.f, d0 = 0.f, s1 = 0.f, d1 = 0.f;
#pragma unroll
  for (int c = 0; c < 16; c++) {
    s0 = fmaf(acc[c], Asl[c], s0);
    d0 = fmaf(acc[c], Adl[c], d0);
    s1 = fmaf(acc[16 + c], Asl[16 + c], s1);
    d1 = fmaf(acc[16 + c], Adl[16 + c], d1);
  }
  as1[n * 2] = s0; as1[n * 2 + 1] = s1;
  ad1[n * 2] = d0; ad1[n * 2 + 1] = d1;
#pragma unroll
  for (int j = 0; j < 4; j++) {
    uint4 u;
    u.x = (unsigned)f2h(acc[j * 8 + 0]) | ((unsigned)f2h(acc[j * 8 + 1]) << 16);
    u.y = (unsigned)f2h(acc[j * 8 + 2]) | ((unsigned)f2h(acc[j * 8 + 3]) << 16);
    u.z = (unsigned)f2h(acc[j * 8 + 4]) | ((unsigned)f2h(acc[j * 8 + 5]) << 16);
    u.w = (unsigned)f2h(acc[j * 8 + 6]) | ((unsigned)f2h(acc[j * 8 + 7]) << 16);
    h1h[(size_t)n * 4 + j] = u;
  }
}

// ------- fused agg1 (split-K=4, shfl) + gemm2 + attn2 + fp16 pack -----------
// block = 16 nodes x 16 threads; r=(half 0-3, cq 0-3); x1 row only in LDS.
__global__ __launch_bounds__(256) void agg1_gemm2(
    const int* __restrict__ rp, const int* __restrict__ csr,
    const float* __restrict__ as, const float* __restrict__ ad,
    const uint4* __restrict__ h1h, const float* __restrict__ b1,
    const float* __restrict__ W2, const float* __restrict__ as2w,
    const float* __restrict__ ad2w, uint4* __restrict__ h2h,
    float* __restrict__ as2, float* __restrict__ ad2, int N) {
  __shared__ float Wl[32 * 40];
  __shared__ float As2l[40], Ad2l[40];
  __shared__ float x1t[16][33];
  __shared__ float h2r[16][41];
  int t = threadIdx.x;
  for (int i = t; i < 320; i += 256)
    ((float4*)Wl)[i] = ((const float4*)W2)[i];
  if (t < 40) { As2l[t] = as2w[t]; Ad2l[t] = ad2w[t]; }
  int nl = t >> 4, r = t & 15;
  int half = r >> 2, cq = r & 3;
  int h = cq >> 1;
  int n = blockIdx.x * 16 + nl;
  float acc[8] = {0, 0, 0, 0, 0, 0, 0, 0};
  float ssum = 0.f;
  if (n < N) {
    int p0 = rp[n], p1 = rp[n + 1];
    float adv = ad[n * 2 + h];
    int p = p0 + half;
    for (; p + 4 < p1; p += 8) {
      int s0 = csr[p], s1 = csr[p + 4];
      float e0 = as[s0 * 2 + h] + adv;
      float e1 = as[s1 * 2 + h] + adv;
      uint4 u0 = h1h[(size_t)s0 * 4 + cq];
      uint4 u1 = h1h[(size_t)s1 * 4 + cq];
      e0 = e0 > 0.f ? e0 : 0.2f * e0;
      e1 = e1 > 0.f ? e1 : 0.2f * e1;
      float x0 = __expf(e0), x1e = __expf(e1);
      ssum += x0 + x1e;
      acc[0] = fmaf(x0, h2f(u0.x & 0xffff), acc[0]);
      acc[1] = fmaf(x0, h2f(u0.x >> 16),    acc[1]);
      acc[2] = fmaf(x0, h2f(u0.y & 0xffff), acc[2]);
      acc[3] = fmaf(x0, h2f(u0.y >> 16),    acc[3]);
      acc[4] = fmaf(x0, h2f(u0.z & 0xffff), acc[4]);
      acc[5] = fmaf(x0, h2f(u0.z >> 16),    acc[5]);
      acc[6] = fmaf(x0, h2f(u0.w & 0xffff), acc[6]);
      acc[7] = fmaf(x0, h2f(u0.w >> 16),    acc[7]);
      acc[0] = fmaf(x1e, h2f(u1.x & 0xffff), acc[0]);
      acc[1] = fmaf(x1e, h2f(u1.x >> 16),    acc[1]);
      acc[2] = fmaf(x1e, h2f(u1.y & 0xffff), acc[2]);
      acc[3] = fmaf(x1e, h2f(u1.y >> 16),    acc[3]);
      acc[4] = fmaf(x1e, h2f(u1.z & 0xffff), acc[4]);
      acc[5] = fmaf(x1e, h2f(u1.z >> 16),    acc[5]);
      acc[6] = fmaf(x1e, h2f(u1.w & 0xffff), acc[6]);
      acc[7] = fmaf(x1e, h2f(u1.w >> 16),    acc[7]);
    }
    for (; p < p1; p += 4) {
      int s = csr[p];
      float e = as[s * 2 + h] + adv;
      uint4 u = h1h[(size_t)s * 4 + cq];
      e = e > 0.f ? e : 0.2f * e;
      float ex = __expf(e);
      ssum += ex;
      acc[0] = fmaf(ex, h2f(u.x & 0xffff), acc[0]);
      acc[1] = fmaf(ex, h2f(u.x >> 16),    acc[1]);
      acc[2] = fmaf(ex, h2f(u.y & 0xffff), acc[2]);
      acc[3] = fmaf(ex, h2f(u.y >> 16),    acc[3]);
      acc[4] = fmaf(ex, h2f(u.z & 0xffff), acc[4]);
      acc[5] = fmaf(ex, h2f(u.z >> 16),    acc[5]);
      acc[6] = fmaf(ex, h2f(u.w & 0xffff), acc[6]);
      acc[7] = fmaf(ex, h2f(u.w >> 16),    acc[7]);
    }
  }
  // combine 4 split-K halves (lanes r^4, r^8 within the 16-lane node group)
#pragma unroll
  for (int j = 0; j < 8; j++) acc[j] += __shfl_xor(acc[j], 4);
  ssum += __shfl_xor(ssum, 4);
#pragma unroll
  for (int j = 0; j < 8; j++) acc[j] += __shfl_xor(acc[j], 8);
  ssum += __shfl_xor(ssum, 8);
  if (n < N && half == 0) {
    float inv = 1.0f / (ssum + 1e-16f);
    float4 ba = ((const float4*)b1)[cq * 2];
    float4 bb = ((const float4*)b1)[cq * 2 + 1];
    int ch0 = cq * 8;
    x1t[nl][ch0 + 0] = fmaxf(fmaf(acc[0], inv, ba.x), 0.f);
    x1t[nl][ch0 + 1] = fmaxf(fmaf(acc[1], inv, ba.y), 0.f);
    x1t[nl][ch0 + 2] = fmaxf(fmaf(acc[2], inv, ba.z), 0.f);
    x1t[nl][ch0 + 3] = fmaxf(fmaf(acc[3], inv, ba.w), 0.f);
    x1t[nl][ch0 + 4] = fmaxf(fmaf(acc[4], inv, bb.x), 0.f);
    x1t[nl][ch0 + 5] = fmaxf(fmaf(acc[5], inv, bb.y), 0.f);
    x1t[nl][ch0 + 6] = fmaxf(fmaf(acc[6], inv, bb.z), 0.f);
    x1t[nl][ch0 + 7] = fmaxf(fmaf(acc[7], inv, bb.w), 0.f);
  }
  __syncthreads();
  // gemm2: 8 threads/node (r<8), 5 out-channels each
  if (n < N && r < 8) {
    float acc2[5] = {0, 0, 0, 0, 0};
    int cb = r * 5;
    for (int k = 0; k < 32; k++) {
      float x = x1t[nl][k];
#pragma unroll
      for (int c = 0; c < 5; c++)
        acc2[c] = fmaf(x, Wl[k * 40 + cb + c], acc2[c]);
    }
    float ss = 0.f, sd = 0.f;
#pragma unroll
    for (int c = 0; c < 5; c++) {
      ss = fmaf(acc2[c], As2l[cb + c], ss);
      sd = fmaf(acc2[c], Ad2l[cb + c], sd);
    }
#pragma unroll
    for (int off = 1; off < 8; off <<= 1) {
      ss += __shfl_xor(ss, off);
      sd += __shfl_xor(sd, off);
    }
    if (r == 0) { as2[n] = ss; ad2[n] = sd; }
#pragma unroll
    for (int c = 0; c < 5; c++) h2r[nl][cb + c] = acc2[c];
  }
  __syncthreads();
  if (n < N && r < 5) {
    const float* hr = h2r[nl] + r * 8;
    uint4 u;
    u.x = (unsigned)f2h(hr[0]) | ((unsigned)f2h(hr[1]) << 16);
    u.y = (unsigned)f2h(hr[2]) | ((unsigned)f2h(hr[3]) << 16);
    u.z = (unsigned)f2h(hr[4]) | ((unsigned)f2h(hr[5]) << 16);
    u.w = (unsigned)f2h(hr[6]) | ((unsigned)f2h(hr[7]) << 16);
    h2h[(size_t)n * 8 + r] = u;  // 128B row stride, 80B used
  }
}

// ---------------- fused softmax+agg, layer 2 (split-K=4, LDS combine) -------
// blocks of 240 active threads (12 nodes x 20); rr = half*5 + cq, half 0-3
__global__ __launch_bounds__(256) void agg2_fused(const int* __restrict__ rp,
                                                  const int* __restrict__ csr,
                                                  const float* __restrict__ as,
                                                  const float* __restrict__ ad,
                                                  const uint4* __restrict__ h2h,
                                                  const float* __restrict__ bias,
                                                  float* __restrict__ outp, int N) {
  __shared__ float part[256][9];
  int t = threadIdx.x;
  int idx = blockIdx.x * A2B + t;
  bool act = (t < A2B) && (idx < N * 20);
  int n = 0, half = 0, cq = 0, p0 = 0, p1 = 0;
  float adv = 0.f;
  if (act) {
    n = idx / 20;
    int rr = idx % 20;
    half = rr / 5;
    cq = rr - half * 5;
    p0 = rp[n]; p1 = rp[n + 1];
    adv = ad[n];
  }
  float acc[8] = {0, 0, 0, 0, 0, 0, 0, 0};
  float ssum = 0.f;
  if (act) {
    int p = p0 + half;
    for (; p + 4 < p1; p += 8) {
      int s0 = csr[p], s1 = csr[p + 4];
      float e0 = as[s0] + adv;
      float e1 = as[s1] + adv;
      uint4 u0 = h2h[(size_t)s0 * 8 + cq];
      uint4 u1 = h2h[(size_t)s1 * 8 + cq];
      e0 = e0 > 0.f ? e0 : 0.2f * e0;
      e1 = e1 > 0.f ? e1 : 0.2f * e1;
      float x0 = __expf(e0), x1e = __expf(e1);
      ssum += x0 + x1e;
      acc[0] = fmaf(x0, h2f(u0.x & 0xffff), acc[0]);
      acc[1] = fmaf(x0, h2f(u0.x >> 16),    acc[1]);
      acc[2] = fmaf(x0, h2f(u0.y & 0xffff), acc[2]);
      acc[3] = fmaf(x0, h2f(u0.y >> 16),    acc[3]);
      acc[4] = fmaf(x0, h2f(u0.z & 0xffff), acc[4]);
      acc[5] = fmaf(x0, h2f(u0.z >> 16),    acc[5]);
      acc[6] = fmaf(x0, h2f(u0.w & 0xffff), acc[6]);
      acc[7] = fmaf(x0, h2f(u0.w >> 16),    acc[7]);
      acc[0] = fmaf(x1e, h2f(u1.x & 0xffff), acc[0]);
      acc[1] = fmaf(x1e, h2f(u1.x >> 16),    acc[1]);
      acc[2] = fmaf(x1e, h2f(u1.y & 0xffff), acc[2]);
      acc[3] = fmaf(x1e, h2f(u1.y >> 16),    acc[3]);
      acc[4] = fmaf(x1e, h2f(u1.z & 0xffff), acc[4]);
      acc[5] = fmaf(x1e, h2f(u1.z >> 16),    acc[5]);
      acc[6] = fmaf(x1e, h2f(u1.w & 0xffff), acc[6]);
      acc[7] = fmaf(x1e, h2f(u1.w >> 16),    acc[7]);
    }
    for (; p < p1; p += 4) {
      int s = csr[p];
      float e = as[s] + adv;
      uint4 u = h2h[(size_t)s * 8 + cq];
      e = e > 0.f ? e : 0.2f * e;
      float ex = __expf(e);
      ssum += ex;
      acc[0] = fmaf(ex, h2f(u.x & 0xffff), acc[0]);
      acc[1] = fmaf(ex, h2f(u.x >> 16),    acc[1]);
      acc[2] = fmaf(ex, h2f(u.y & 0xffff), acc[2]);
      acc[3] = fmaf(ex, h2f(u.y >> 16),    acc[3]);
      acc[4] = fmaf(ex, h2f(u.z & 0xffff), acc[4]);
      acc[5] = fmaf(ex, h2f(u.z >> 16),    acc[5]);
      acc[6] = fmaf(ex, h2f(u.w & 0xffff), acc[6]);
      acc[7] = fmaf(ex, h2f(u.w >> 16),    acc[7]);
    }
  }
  if (act && half) {
#pragma unroll
    for (int j = 0; j < 8; j++) part[t][j] = acc[j];
    part[t][8] = ssum;
  }
  __syncthreads();
  if (act && half == 0) {
#pragma unroll
    for (int j = 0; j < 8; j++)
      acc[j] += part[t + 5][j] + part[t + 10][j] + part[t + 15][j];
    ssum += part[t + 5][8] + part[t + 10][8] + part[t + 15][8];
    float inv = 1.0f / (ssum + 1e-16f);
    const float4* b4 = (const float4*)bias;
    float4 ba = b4[cq * 2], bb = b4[cq * 2 + 1];
    float4 r0, r1;
    r0.x = fmaf(acc[0], inv, ba.x);
    r0.y = fmaf(acc[1], inv, ba.y);
    r0.z = fmaf(acc[2], inv, ba.z);
    r0.w = fmaf(acc[3], inv, ba.w);
    r1.x = fmaf(acc[4], inv, bb.x);
    r1.y = fmaf(acc[5], inv, bb.y);
    r1.z = fmaf(acc[6], inv, bb.z);
    r1.w = fmaf(acc[7], inv, bb.w);
    ((float4*)outp)[(size_t)n * 10 + cq * 2]     = r0;
    ((float4*)outp)[(size_t)n * 10 + cq * 2 + 1] = r1;
  }
}

// ---------------- host launcher ----------------
extern "C" void kernel_launch(void* const* d_in, const int* in_sizes, int n_in,
                              void* d_out, int out_size, void* d_ws, size_t ws_size,
                              hipStream_t stream) {
  const float* X    = (const float*)d_in[0];
  const long long* eg64 = (const long long*)d_in[1];
  const int* eg32   = (const int*)d_in[1];
  const float* W1   = (const float*)d_in[3];
  const float* as1w = (const float*)d_in[4];
  const float* ad1w = (const float*)d_in[5];
  const float* b1   = (const float*)d_in[6];
  const float* W2   = (const float*)d_in[7];
  const float* as2w = (const float*)d_in[8];
  const float* ad2w = (const float*)d_in[9];
  const float* b2   = (const float*)d_in[10];
  float* out = (float*)d_out;

  const int N  = in_sizes[0] / 128;
  const int E  = in_sizes[1] / 2;
  const int EN = E + N;
  const int NB2 = (N + CB_SZ - 1) / CB_SZ;
  const int NWG = (EN + CHUNK - 1) / CHUNK;
  const int NH  = NB2 * NWG;

  char* wbase = (char*)d_ws;
  size_t off = 0;
  auto alloc = [&](size_t bytes) -> void* {
    void* p = wbase + off;
    off += (bytes + 255) & ~(size_t)255;
    return p;
  };

  uint4* h1h = (uint4*)alloc((size_t)N * 64);        // fp16 h1, 64B rows
  uint4* h2h = (uint4*)alloc((size_t)N * 128);       // fp16 h2, 128B padded rows
  float* as1 = (float*)alloc((size_t)N * 2 * 4);
  float* ad1 = (float*)alloc((size_t)N * 2 * 4);
  float* as2 = (float*)alloc((size_t)N * 4);
  float* ad2 = (float*)alloc((size_t)N * 4);
  int* rp     = (int*)alloc((size_t)(N + 1) * 4);
  int* histg  = (int*)alloc((size_t)NH * 4);
  int* hists  = (int*)alloc((size_t)(NH + 1) * 4);
  int* bsum   = (int*)alloc(1024 * 4);
  int* boff   = (int*)alloc(1024 * 4);
  int* csr    = (int*)alloc((size_t)EN * 4);
  int* tmp    = (int*)alloc((size_t)EN * 4);
  (void)ws_size; (void)n_in; (void)out_size;

  const int gN  = (N + 255) / 256;
  const int nbH = (NH + 1023) / 1024;

  // CSR build (atomic-free; is64 detected per-WG, block-uniform)
  chunk_hist<<<NWG, 256, 0, stream>>>(eg64, eg32, E, N, NWG, histg);
  scan_blocks<<<nbH, 1024, 0, stream>>>(histg, hists, bsum, NH);
  scan_sums<<<1, 64, 0, stream>>>(bsum, boff, nbH);
  scan_add<<<nbH, 1024, 0, stream>>>(hists, boff, NH, EN);
  chunk_scatter<<<NWG, 256, 0, stream>>>(eg64, eg32, E, N, NWG, hists, tmp);
  bucket_rp_sort<<<NB2, 256, 0, stream>>>(hists, NWG, tmp, rp, csr, N, EN);

  // Layer 1 projection
  gemm1f<<<gN, 256, 0, stream>>>(X, W1, as1w, ad1w, h1h, as1, ad1, N);
  // agg1 + gemm2 + attn2 fused (x1 never touches global)
  agg1_gemm2<<<(N + 15) / 16, 256, 0, stream>>>(rp, csr, as1, ad1, h1h, b1,
                                                W2, as2w, ad2w, h2h, as2, ad2, N);
  // Layer 2 aggregation -> output
  agg2_fused<<<(N * 20 + A2B - 1) / A2B, 256, 0, stream>>>(rp, csr, as2, ad2,
                                                           h2h, b2, out, N);
}